// Round 3
// baseline (1627.216 us; speedup 1.0000x reference)
//
#include <hip/hip_runtime.h>
#include <hip/hip_bf16.h>

#define BSZ 16384
#define DIM 512
#define NEMB 8192
#define NEG 0.01f
#define NSPLIT 8
#define NG 128   // 8 nt-tiles * 16 kk-steps

typedef __attribute__((ext_vector_type(8))) short short8;
typedef __attribute__((ext_vector_type(4))) float f32x4;

typedef const __attribute__((address_space(1))) void GVT;
typedef __attribute__((address_space(3))) void LVT;

__device__ __forceinline__ void gl_lds16(const void* g, void* l) {
    __builtin_amdgcn_global_load_lds((GVT*)g, (LVT*)l, 16, 0, 0);
}

__device__ __forceinline__ float bf2f(unsigned short u) {
    union { unsigned int i; float f; } c; c.i = ((unsigned int)u) << 16; return c.f;
}
__device__ __forceinline__ unsigned short f2bf(float f) {
    union { __hip_bfloat16 h; unsigned short u; } c; c.h = __float2bfloat16(f); return c.u;
}
// monotone-orderable uint key for a float
__device__ __forceinline__ unsigned int fkey(float f) {
    unsigned int u = __float_as_uint(f);
    return u ^ ((unsigned int)((int)u >> 31) | 0x80000000u);
}

// barrier that does NOT drain vmcnt: global prefetch loads stay in flight.
// Cross-wave deps here are only via LDS -> lgkmcnt(0) is sufficient.
__device__ __forceinline__ void lds_barrier() {
    asm volatile("s_waitcnt lgkmcnt(0)\ns_barrier" ::: "memory");
}

// ---------------- fused fp32 -> bf16 convert for all 5 tensors ----------------
__global__ void k_convert_all(const float* __restrict__ eeg, const float* __restrict__ mel,
                              const float* __restrict__ emb, const float* __restrict__ W2,
                              const float* __restrict__ W1,
                              unsigned short* __restrict__ o_eeg, unsigned short* __restrict__ o_mel,
                              unsigned short* __restrict__ o_emb, unsigned short* __restrict__ o_w2,
                              unsigned short* __restrict__ o_w1) {
    const int n_big = BSZ * DIM / 4;
    const int n_mid = NEMB * DIM / 4;
    const int n_w1  = DIM * DIM / 4;
    const int total = n_big * 2 + n_mid * 2 + n_w1;
    for (int i = blockIdx.x * blockDim.x + threadIdx.x; i < total; i += gridDim.x * blockDim.x) {
        const float* src; unsigned short* dst; int j = i;
        if (j < n_big) { src = eeg; dst = o_eeg; }
        else if ((j -= n_big) < n_big) { src = mel; dst = o_mel; }
        else if ((j -= n_big) < n_mid) { src = emb; dst = o_emb; }
        else if ((j -= n_mid) < n_mid) { src = W2; dst = o_w2; }
        else { j -= n_mid; src = W1; dst = o_w1; }
        float4 v = ((const float4*)src)[j];
        ushort4 o;
        o.x = f2bf(v.x); o.y = f2bf(v.y); o.z = f2bf(v.z); o.w = f2bf(v.w);
        ((ushort4*)dst)[j] = o;
    }
}

// ---------------- embedding row norms (fp32) ----------------
__global__ void k_enorm(const float* __restrict__ emb, float* __restrict__ enorm) {
    int row = blockIdx.x * 4 + (threadIdx.x >> 6);
    int lane = threadIdx.x & 63;
    const float4* p = (const float4*)(emb + row * DIM) + lane * 2;
    float4 a = p[0], b = p[1];
    float s = a.x*a.x + a.y*a.y + a.z*a.z + a.w*a.w
            + b.x*b.x + b.y*b.y + b.z*b.z + b.w*b.w;
    #pragma unroll
    for (int d = 1; d < 64; d <<= 1) s += __shfl_xor(s, d);
    if (lane == 0) enorm[row] = s;
}

// ---------------- h = LeakyReLU(eeg @ W1^T + b1), bf16 out ----------------
__launch_bounds__(256, 2)
__global__ void k_hgemm(const unsigned short* __restrict__ A,
                        const unsigned short* __restrict__ B,
                        const float* __restrict__ b1,
                        unsigned short* __restrict__ H) {
    __shared__ __align__(16) unsigned short sA[4096], sB[4096];
    int tid = threadIdx.x;
    int w = tid >> 6, lane = tid & 63;
    int wr = w >> 1, wc = w & 1;
    int lquad = lane >> 4, l15 = lane & 15;
    int mt = blockIdx.x >> 2, nt = blockIdx.x & 3;
    int m0 = mt * 128, n0 = nt * 128;

    int e0 = w * 512 + lane * 8;
    int r0 = e0 >> 5, ce = e0 & 31;
    const unsigned short* gA0 = A + (m0 + r0) * DIM + ce;
    const unsigned short* gA1 = gA0 + 64 * DIM;
    const unsigned short* gB0 = B + (n0 + r0) * DIM + ce;
    const unsigned short* gB1 = gB0 + 64 * DIM;
    unsigned short* lA0 = sA + w * 512;  unsigned short* lA1 = sA + (w + 4) * 512;
    unsigned short* lB0 = sB + w * 512;  unsigned short* lB1 = sB + (w + 4) * 512;

    int offA[4], offB[4];
    #pragma unroll
    for (int i = 0; i < 4; i++) {
        offA[i] = (wr * 64 + i * 16 + l15) * 32 + lquad * 8;
        offB[i] = (wc * 64 + i * 16 + l15) * 32 + lquad * 8;
    }

    f32x4 acc[4][4];
    #pragma unroll
    for (int mi = 0; mi < 4; mi++)
        #pragma unroll
        for (int ni = 0; ni < 4; ni++) acc[mi][ni] = 0;

    for (int kk = 0; kk < 16; kk++) {
        gl_lds16(gA0, lA0); gl_lds16(gA1, lA1);
        gl_lds16(gB0, lB0); gl_lds16(gB1, lB1);
        gA0 += 32; gA1 += 32; gB0 += 32; gB1 += 32;
        __syncthreads();
        short8 af[4], bf_[4];
        #pragma unroll
        for (int i = 0; i < 4; i++) {
            af[i]  = *(const short8*)&sA[offA[i]];
            bf_[i] = *(const short8*)&sB[offB[i]];
        }
        #pragma unroll
        for (int mi = 0; mi < 4; mi++)
            #pragma unroll
            for (int ni = 0; ni < 4; ni++)
                acc[mi][ni] = __builtin_amdgcn_mfma_f32_16x16x32_bf16(af[mi], bf_[ni], acc[mi][ni], 0, 0, 0);
        __syncthreads();
    }

    #pragma unroll
    for (int ni = 0; ni < 4; ni++) {
        int col = n0 + wc * 64 + ni * 16 + l15;
        float bv = b1[col];
        #pragma unroll
        for (int mi = 0; mi < 4; mi++) {
            int rowb = m0 + wr * 64 + mi * 16 + lquad * 4;
            #pragma unroll
            for (int rg = 0; rg < 4; rg++) {
                float v = acc[mi][ni][rg] + bv;
                v = v >= 0.f ? v : NEG * v;
                H[(rowb + rg) * DIM + col] = f2bf(v);
            }
        }
    }
}

// ======== register-staged, depth-2 pipelined GEMM bodies ========
// At iter G: issue global loads for G+2 into reg slot SL, MFMA tile G from
// LDS buf SL, ds_write slot SO (=G+1 data) into LDS buf SO, barrier (lgkm only).

#define PIPE_LOAD(SL, G2) \
    if ((G2) < NG) { \
        const unsigned short* pa = gA + (((G2) & 15) << 5); \
        rA0[SL] = *(const uint4*)pa; rA1[SL] = *(const uint4*)(pa + 64 * DIM); \
        const unsigned short* pb = gB + ((G2) >> 4) * (128 * DIM) + (((G2) & 15) << 5); \
        rB0[SL] = *(const uint4*)pb; rB1[SL] = *(const uint4*)(pb + 64 * DIM); \
    }

#define PIPE_COMPUTE(SL) \
    { short8 af[4], bf_[4]; \
      _Pragma("unroll") for (int i = 0; i < 4; i++) { \
          af[i]  = *(const short8*)&sA[SL][offA[i]]; \
          bf_[i] = *(const short8*)&sB[SL][offB[i]]; \
      } \
      _Pragma("unroll") for (int mi = 0; mi < 4; mi++) \
          _Pragma("unroll") for (int ni = 0; ni < 4; ni++) \
              acc[mi][ni] = __builtin_amdgcn_mfma_f32_16x16x32_bf16(af[mi], bf_[ni], acc[mi][ni], 0, 0, 0); }

#define PIPE_STORE(SO, G) \
    if ((G) + 1 < NG) { \
        *(uint4*)&sA[SO][e0] = rA0[SO]; *(uint4*)&sA[SO][e0 + 2048] = rA1[SO]; \
        *(uint4*)&sB[SO][e0] = rB0[SO]; *(uint4*)&sB[SO][e0 + 2048] = rB1[SO]; \
    }

// ---------------- GEMM 1: distances -> packed argmin per row ----------------
__launch_bounds__(256, 2)
__global__ void k_dist(const unsigned short* __restrict__ Amel,
                       const unsigned short* __restrict__ Bemb,
                       const float* __restrict__ enorm,
                       unsigned int* __restrict__ p_pmin) {
    __shared__ __align__(16) unsigned short sA[2][4096], sB[2][4096];
    __shared__ unsigned int red_pm[256];
    int tid = threadIdx.x;
    int w = tid >> 6, lane = tid & 63;
    int wr = w >> 1, wc = w & 1;
    int lquad = lane >> 4, l15 = lane & 15;
    int mt = blockIdx.x >> 3, split = blockIdx.x & 7;
    int m0 = mt * 128, nbase = split * (NEMB / NSPLIT);

    int e0 = w * 512 + lane * 8;
    int r0 = e0 >> 5, ce = e0 & 31;
    const unsigned short* gA = Amel + (m0 + r0) * DIM + ce;
    const unsigned short* gB = Bemb + (nbase + r0) * DIM + ce;

    int offA[4], offB[4];
    #pragma unroll
    for (int i = 0; i < 4; i++) {
        offA[i] = (wr * 64 + i * 16 + l15) * 32 + lquad * 8;
        offB[i] = (wc * 64 + i * 16 + l15) * 32 + lquad * 8;
    }

    uint4 rA0[2], rA1[2], rB0[2], rB1[2];
    // prologue: load g=0 (slot0), g=1 (slot1); commit slot0 to LDS buf0
    PIPE_LOAD(0, 0)
    PIPE_LOAD(1, 1)
    *(uint4*)&sA[0][e0] = rA0[0]; *(uint4*)&sA[0][e0 + 2048] = rA1[0];
    *(uint4*)&sB[0][e0] = rB0[0]; *(uint4*)&sB[0][e0 + 2048] = rB1[0];
    lds_barrier();

    f32x4 acc[4][4];
    #pragma unroll
    for (int mi = 0; mi < 4; mi++)
        #pragma unroll
        for (int ni = 0; ni < 4; ni++) acc[mi][ni] = 0;

    unsigned int pmin[16];
    #pragma unroll
    for (int r = 0; r < 16; r++) pmin[r] = 0xFFFFFFFFu;

    for (int g = 0; g < NG; g += 2) {
        // ---- iter g (SL=0, SO=1) ----
        PIPE_LOAD(0, g + 2)
        PIPE_COMPUTE(0)
        PIPE_STORE(1, g)
        lds_barrier();
        // ---- iter g+1 (SL=1, SO=0) ----
        PIPE_LOAD(1, g + 3)
        PIPE_COMPUTE(1)
        PIPE_STORE(0, g + 1)
        if (((g + 1) & 15) == 15) {
            int c0 = nbase + ((g + 1) >> 4) * 128;
            #pragma unroll
            for (int ni = 0; ni < 4; ni++) {
                int col = c0 + wc * 64 + ni * 16 + l15;
                float en = enorm[col] - 512.0f;
                unsigned int cl = (unsigned int)col;
                #pragma unroll
                for (int mi = 0; mi < 4; mi++)
                    #pragma unroll
                    for (int rg = 0; rg < 4; rg++) {
                        float d = fmaf(-2.f, acc[mi][ni][rg], en);
                        unsigned int pk = (fkey(d) & 0xFFFFE000u) | cl;
                        int r = mi * 4 + rg;
                        pmin[r] = pmin[r] < pk ? pmin[r] : pk;
                        acc[mi][ni][rg] = 0.f;
                    }
            }
        }
        lds_barrier();
    }

    #pragma unroll
    for (int r = 0; r < 16; r++)
        #pragma unroll
        for (int d = 1; d < 16; d <<= 1) {
            unsigned int o = (unsigned int)__shfl_xor((int)pmin[r], d);
            pmin[r] = pmin[r] < o ? pmin[r] : o;
        }
    if (l15 == 0) {
        #pragma unroll
        for (int mi = 0; mi < 4; mi++)
            #pragma unroll
            for (int rg = 0; rg < 4; rg++)
                red_pm[(wr * 64 + mi * 16 + lquad * 4 + rg) * 2 + wc] = pmin[mi * 4 + rg];
    }
    __syncthreads();
    if (tid < 128) {
        unsigned int a = red_pm[2 * tid], b = red_pm[2 * tid + 1];
        p_pmin[split * BSZ + m0 + tid] = a < b ? a : b;
    }
}

// ---------------- GEMM 2: logits -> sum(exp) + packed argmax per row ----------------
__launch_bounds__(256, 2)
__global__ void k_logits(const unsigned short* __restrict__ Ah,
                         const unsigned short* __restrict__ Bw2,
                         const float* __restrict__ b2,
                         float* __restrict__ p_s,
                         unsigned int* __restrict__ p_pmax) {
    __shared__ __align__(16) unsigned short sA[2][4096], sB[2][4096];
    __shared__ float red_s[256];
    __shared__ unsigned int red_pm[256];
    int tid = threadIdx.x;
    int w = tid >> 6, lane = tid & 63;
    int wr = w >> 1, wc = w & 1;
    int lquad = lane >> 4, l15 = lane & 15;
    int mt = blockIdx.x >> 3, split = blockIdx.x & 7;
    int m0 = mt * 128, nbase = split * (NEMB / NSPLIT);

    int e0 = w * 512 + lane * 8;
    int r0 = e0 >> 5, ce = e0 & 31;
    const unsigned short* gA = Ah + (m0 + r0) * DIM + ce;
    const unsigned short* gB = Bw2 + (nbase + r0) * DIM + ce;

    int offA[4], offB[4];
    #pragma unroll
    for (int i = 0; i < 4; i++) {
        offA[i] = (wr * 64 + i * 16 + l15) * 32 + lquad * 8;
        offB[i] = (wc * 64 + i * 16 + l15) * 32 + lquad * 8;
    }

    uint4 rA0[2], rA1[2], rB0[2], rB1[2];
    PIPE_LOAD(0, 0)
    PIPE_LOAD(1, 1)
    *(uint4*)&sA[0][e0] = rA0[0]; *(uint4*)&sA[0][e0 + 2048] = rA1[0];
    *(uint4*)&sB[0][e0] = rB0[0]; *(uint4*)&sB[0][e0 + 2048] = rB1[0];
    lds_barrier();

    f32x4 acc[4][4];
    #pragma unroll
    for (int mi = 0; mi < 4; mi++)
        #pragma unroll
        for (int ni = 0; ni < 4; ni++) acc[mi][ni] = 0;

    float s[16];
    unsigned int pmax[16];
    #pragma unroll
    for (int r = 0; r < 16; r++) { s[r] = 0.f; pmax[r] = 0u; }

    for (int g = 0; g < NG; g += 2) {
        // ---- iter g (SL=0, SO=1) ----
        PIPE_LOAD(0, g + 2)
        PIPE_COMPUTE(0)
        PIPE_STORE(1, g)
        lds_barrier();
        // ---- iter g+1 (SL=1, SO=0) ----
        PIPE_LOAD(1, g + 3)
        PIPE_COMPUTE(1)
        PIPE_STORE(0, g + 1)
        if (((g + 1) & 15) == 15) {
            int c0 = nbase + ((g + 1) >> 4) * 128;
            #pragma unroll
            for (int ni = 0; ni < 4; ni++) {
                int col = c0 + wc * 64 + ni * 16 + l15;
                float bb = b2[col];
                unsigned int ic = (unsigned int)(NEMB - 1 - col);
                #pragma unroll
                for (int mi = 0; mi < 4; mi++)
                    #pragma unroll
                    for (int rg = 0; rg < 4; rg++) {
                        float logit = acc[mi][ni][rg] + bb;
                        int r = mi * 4 + rg;
                        s[r] += __expf(logit);
                        unsigned int pk = (fkey(logit) & 0xFFFFE000u) | ic;
                        pmax[r] = pmax[r] > pk ? pmax[r] : pk;
                        acc[mi][ni][rg] = 0.f;
                    }
            }
        }
        lds_barrier();
    }

    #pragma unroll
    for (int r = 0; r < 16; r++)
        #pragma unroll
        for (int d = 1; d < 16; d <<= 1) {
            s[r] += __shfl_xor(s[r], d);
            unsigned int o = (unsigned int)__shfl_xor((int)pmax[r], d);
            pmax[r] = pmax[r] > o ? pmax[r] : o;
        }
    if (l15 == 0) {
        #pragma unroll
        for (int mi = 0; mi < 4; mi++)
            #pragma unroll
            for (int rg = 0; rg < 4; rg++) {
                int r2 = (wr * 64 + mi * 16 + lquad * 4 + rg) * 2 + wc;
                red_s[r2] = s[mi * 4 + rg];
                red_pm[r2] = pmax[mi * 4 + rg];
            }
    }
    __syncthreads();
    if (tid < 128) {
        float S = red_s[2 * tid] + red_s[2 * tid + 1];
        unsigned int a = red_pm[2 * tid], b = red_pm[2 * tid + 1];
        int pidx = split * BSZ + m0 + tid;
        p_s[pidx] = S;
        p_pmax[pidx] = a > b ? a : b;
    }
}

// ---------------- merge split partials per row ----------------
__global__ void k_merge(const float* __restrict__ p_s, const unsigned int* __restrict__ p_pmax,
                        const unsigned int* __restrict__ p_pmin,
                        int* __restrict__ mel_idx, float* __restrict__ lse,
                        float* __restrict__ match) {
    int r = blockIdx.x * blockDim.x + threadIdx.x;
    if (r >= BSZ) return;
    float S = 0.f; unsigned int PM = 0u, PN = 0xFFFFFFFFu;
    #pragma unroll
    for (int sp = 0; sp < NSPLIT; sp++) {
        S += p_s[sp * BSZ + r];
        unsigned int a = p_pmax[sp * BSZ + r];
        PM = PM > a ? PM : a;
        unsigned int b = p_pmin[sp * BSZ + r];
        PN = PN < b ? PN : b;
    }
    int eidx = (NEMB - 1) - (int)(PM & 0x1FFFu);
    int midx = (int)(PN & 0x1FFFu);
    mel_idx[r] = midx;
    lse[r] = __logf(S);
    match[r] = (eidx == midx) ? 1.f : 0.f;
}

// ---------------- gather picked logit, per-row loss ----------------
__device__ __forceinline__ float dot2bf(unsigned int h, unsigned int w) {
    return bf2f((unsigned short)(h & 0xffff)) * bf2f((unsigned short)(w & 0xffff))
         + bf2f((unsigned short)(h >> 16))    * bf2f((unsigned short)(w >> 16));
}

__global__ void k_gather(const unsigned short* __restrict__ H,
                         const unsigned short* __restrict__ W2b,
                         const float* __restrict__ b2,
                         const int* __restrict__ mel_idx,
                         const float* __restrict__ lse,
                         float* __restrict__ loss) {
    int r = blockIdx.x * 4 + (threadIdx.x >> 6);
    int lane = threadIdx.x & 63;
    int idx = mel_idx[r];
    uint4 hv = *(const uint4*)(H + r * DIM + lane * 8);
    uint4 wv = *(const uint4*)(W2b + idx * DIM + lane * 8);
    float s = dot2bf(hv.x, wv.x) + dot2bf(hv.y, wv.y) + dot2bf(hv.z, wv.z) + dot2bf(hv.w, wv.w);
    #pragma unroll
    for (int d = 1; d < 64; d <<= 1) s += __shfl_xor(s, d);
    if (lane == 0) loss[r] = lse[r] - (s + b2[idx]);
}

// ---------------- final scalar reduction ----------------
__global__ void k_reduce(const float* __restrict__ loss, const float* __restrict__ match,
                         float* __restrict__ out) {
    __shared__ float sl[256], sm[256];
    int tid = threadIdx.x;
    float a = 0.f, b = 0.f;
    for (int i = tid; i < BSZ; i += 256) { a += loss[i]; b += match[i]; }
    sl[tid] = a; sm[tid] = b;
    __syncthreads();
    for (int s = 128; s > 0; s >>= 1) {
        if (tid < s) { sl[tid] += sl[tid + s]; sm[tid] += sm[tid + s]; }
        __syncthreads();
    }
    if (tid == 0) { out[0] = sl[0] / (float)BSZ; out[1] = sm[0] / (float)BSZ; }
}

extern "C" void kernel_launch(void* const* d_in, const int* in_sizes, int n_in,
                              void* d_out, int out_size, void* d_ws, size_t ws_size,
                              hipStream_t stream) {
    const float* eeg = (const float*)d_in[0];
    const float* mel = (const float*)d_in[1];
    const float* emb = (const float*)d_in[2];
    const float* W1  = (const float*)d_in[3];
    const float* b1  = (const float*)d_in[4];
    const float* W2  = (const float*)d_in[5];
    const float* b2  = (const float*)d_in[6];
    float* out = (float*)d_out;

    unsigned short* ws_mel = (unsigned short*)d_ws;
    unsigned short* ws_eeg = ws_mel + (size_t)BSZ * DIM;
    unsigned short* ws_h   = ws_eeg + (size_t)BSZ * DIM;
    unsigned short* ws_emb = ws_h   + (size_t)BSZ * DIM;
    unsigned short* ws_w2  = ws_emb + (size_t)NEMB * DIM;
    unsigned short* ws_w1  = ws_w2  + (size_t)NEMB * DIM;
    float* ws_en  = (float*)(ws_w1 + (size_t)DIM * DIM);
    float* p_s    = ws_en + NEMB;
    unsigned int* p_pmax = (unsigned int*)(p_s + (size_t)NSPLIT * BSZ);
    unsigned int* p_pmin = p_pmax + (size_t)NSPLIT * BSZ;
    int*   mel_i  = (int*)(p_pmin + (size_t)NSPLIT * BSZ);
    float* lse    = (float*)(mel_i + BSZ);
    float* match  = lse + BSZ;
    float* loss   = match + BSZ;

    k_convert_all<<<1024, 256, 0, stream>>>(eeg, mel, emb, W2, W1,
                                            ws_eeg, ws_mel, ws_emb, ws_w2, ws_w1);
    k_enorm<<<NEMB / 4, 256, 0, stream>>>(emb, ws_en);
    k_hgemm<<<(BSZ / 128) * (DIM / 128), 256, 0, stream>>>(ws_eeg, ws_w1, b1, ws_h);
    k_dist<<<(BSZ / 128) * NSPLIT, 256, 0, stream>>>(ws_mel, ws_emb, ws_en, p_pmin);
    k_logits<<<(BSZ / 128) * NSPLIT, 256, 0, stream>>>(ws_h, ws_w2, b2, p_s, p_pmax);
    k_merge<<<BSZ / 256, 256, 0, stream>>>(p_s, p_pmax, p_pmin, mel_i, lse, match);
    k_gather<<<BSZ / 4, 256, 0, stream>>>(ws_h, ws_w2, b2, mel_i, lse, loss);
    k_reduce<<<1, 256, 0, stream>>>(loss, match, out);
}

// Round 4
// 561.048 us; speedup vs baseline: 2.9003x; 2.9003x over previous
//
#include <hip/hip_runtime.h>
#include <hip/hip_bf16.h>

#define BSZ 16384
#define DIM 512
#define NEMB 8192
#define NEG 0.01f
#define NSPLIT 8
#define NG 128   // 8 nt-tiles * 16 kk-steps

typedef __attribute__((ext_vector_type(8))) short short8;
typedef __attribute__((ext_vector_type(4))) float f32x4;

typedef const __attribute__((address_space(1))) void GVT;
typedef __attribute__((address_space(3))) void LVT;

__device__ __forceinline__ void gl_lds16(const void* g, void* l) {
    __builtin_amdgcn_global_load_lds((GVT*)g, (LVT*)l, 16, 0, 0);
}

__device__ __forceinline__ float bf2f(unsigned short u) {
    union { unsigned int i; float f; } c; c.i = ((unsigned int)u) << 16; return c.f;
}
__device__ __forceinline__ unsigned short f2bf(float f) {
    union { __hip_bfloat16 h; unsigned short u; } c; c.h = __float2bfloat16(f); return c.u;
}
// monotone-orderable uint key for a float
__device__ __forceinline__ unsigned int fkey(float f) {
    unsigned int u = __float_as_uint(f);
    return u ^ ((unsigned int)((int)u >> 31) | 0x80000000u);
}

// barrier with 4 global_load_lds left in flight (the g+1 tile's loads).
// lgkmcnt(0) covers LDS init writes on first use; near-free in steady state.
__device__ __forceinline__ void pipe_barrier() {
    asm volatile("s_waitcnt vmcnt(4) lgkmcnt(0)\ns_barrier" ::: "memory");
}
// plain barrier: protects LDS buffer reuse; no memory-counter drain needed
// (all ds_reads were consumed by MFMA before reaching here).
__device__ __forceinline__ void plain_barrier() {
    asm volatile("s_barrier" ::: "memory");
}

// issue the 4 async global->LDS loads for tile index G into LDS buffer BUF.
// G is wrapped (&127) so tail iterations issue harmless re-loads, keeping
// the vmcnt(4) bookkeeping exact.
#define ISSUE_TILE(G, BUF) do { \
    int Gm = (G) & 127; \
    const unsigned short* pa = gA + ((Gm & 15) << 5); \
    const unsigned short* pb = gB + (Gm >> 4) * (128 * DIM) + ((Gm & 15) << 5); \
    gl_lds16(pa, &sA[BUF][uA]); \
    gl_lds16(pa + 64 * DIM, &sA[BUF][uA + 2048]); \
    gl_lds16(pb, &sB[BUF][uA]); \
    gl_lds16(pb + 64 * DIM, &sB[BUF][uA + 2048]); \
} while (0)

#define COMPUTE_TILE(BUF) do { \
    short8 af[4], bfv[4]; \
    _Pragma("unroll") for (int i = 0; i < 4; i++) { \
        af[i]  = *(const short8*)&sA[BUF][offA[i]]; \
        bfv[i] = *(const short8*)&sB[BUF][offB[i]]; \
    } \
    _Pragma("unroll") for (int mi = 0; mi < 4; mi++) \
        _Pragma("unroll") for (int ni = 0; ni < 4; ni++) \
            acc[mi][ni] = __builtin_amdgcn_mfma_f32_16x16x32_bf16(af[mi], bfv[ni], acc[mi][ni], 0, 0, 0); \
} while (0)

// ---------------- fused fp32 -> bf16 convert for all 5 tensors ----------------
__global__ void k_convert_all(const float* __restrict__ eeg, const float* __restrict__ mel,
                              const float* __restrict__ emb, const float* __restrict__ W2,
                              const float* __restrict__ W1,
                              unsigned short* __restrict__ o_eeg, unsigned short* __restrict__ o_mel,
                              unsigned short* __restrict__ o_emb, unsigned short* __restrict__ o_w2,
                              unsigned short* __restrict__ o_w1) {
    const int n_big = BSZ * DIM / 4;
    const int n_mid = NEMB * DIM / 4;
    const int n_w1  = DIM * DIM / 4;
    const int total = n_big * 2 + n_mid * 2 + n_w1;
    for (int i = blockIdx.x * blockDim.x + threadIdx.x; i < total; i += gridDim.x * blockDim.x) {
        const float* src; unsigned short* dst; int j = i;
        if (j < n_big) { src = eeg; dst = o_eeg; }
        else if ((j -= n_big) < n_big) { src = mel; dst = o_mel; }
        else if ((j -= n_big) < n_mid) { src = emb; dst = o_emb; }
        else if ((j -= n_mid) < n_mid) { src = W2; dst = o_w2; }
        else { j -= n_mid; src = W1; dst = o_w1; }
        float4 v = ((const float4*)src)[j];
        ushort4 o;
        o.x = f2bf(v.x); o.y = f2bf(v.y); o.z = f2bf(v.z); o.w = f2bf(v.w);
        ((ushort4*)dst)[j] = o;
    }
}

// ---------------- embedding row norms (fp32) ----------------
__global__ void k_enorm(const float* __restrict__ emb, float* __restrict__ enorm) {
    int row = blockIdx.x * 4 + (threadIdx.x >> 6);
    int lane = threadIdx.x & 63;
    const float4* p = (const float4*)(emb + row * DIM) + lane * 2;
    float4 a = p[0], b = p[1];
    float s = a.x*a.x + a.y*a.y + a.z*a.z + a.w*a.w
            + b.x*b.x + b.y*b.y + b.z*b.z + b.w*b.w;
    #pragma unroll
    for (int d = 1; d < 64; d <<= 1) s += __shfl_xor(s, d);
    if (lane == 0) enorm[row] = s;
}

// ---------------- h = LeakyReLU(eeg @ W1^T + b1), bf16 out ----------------
__launch_bounds__(256, 2)
__global__ void k_hgemm(const unsigned short* __restrict__ A,
                        const unsigned short* __restrict__ B,
                        const float* __restrict__ b1,
                        unsigned short* __restrict__ H) {
    __shared__ __align__(16) unsigned short sA[4096], sB[4096];
    int tid = threadIdx.x;
    int w = tid >> 6, lane = tid & 63;
    int wr = w >> 1, wc = w & 1;
    int lquad = lane >> 4, l15 = lane & 15;
    int mt = blockIdx.x >> 2, nt = blockIdx.x & 3;
    int m0 = mt * 128, n0 = nt * 128;

    int e0 = w * 512 + lane * 8;
    int r0 = e0 >> 5, ce = e0 & 31;
    const unsigned short* gA0 = A + (m0 + r0) * DIM + ce;
    const unsigned short* gA1 = gA0 + 64 * DIM;
    const unsigned short* gB0 = B + (n0 + r0) * DIM + ce;
    const unsigned short* gB1 = gB0 + 64 * DIM;
    unsigned short* lA0 = sA + w * 512;  unsigned short* lA1 = sA + (w + 4) * 512;
    unsigned short* lB0 = sB + w * 512;  unsigned short* lB1 = sB + (w + 4) * 512;

    int offA[4], offB[4];
    #pragma unroll
    for (int i = 0; i < 4; i++) {
        offA[i] = (wr * 64 + i * 16 + l15) * 32 + lquad * 8;
        offB[i] = (wc * 64 + i * 16 + l15) * 32 + lquad * 8;
    }

    f32x4 acc[4][4];
    #pragma unroll
    for (int mi = 0; mi < 4; mi++)
        #pragma unroll
        for (int ni = 0; ni < 4; ni++) acc[mi][ni] = 0;

    for (int kk = 0; kk < 16; kk++) {
        gl_lds16(gA0, lA0); gl_lds16(gA1, lA1);
        gl_lds16(gB0, lB0); gl_lds16(gB1, lB1);
        gA0 += 32; gA1 += 32; gB0 += 32; gB1 += 32;
        __syncthreads();
        short8 af[4], bf_[4];
        #pragma unroll
        for (int i = 0; i < 4; i++) {
            af[i]  = *(const short8*)&sA[offA[i]];
            bf_[i] = *(const short8*)&sB[offB[i]];
        }
        #pragma unroll
        for (int mi = 0; mi < 4; mi++)
            #pragma unroll
            for (int ni = 0; ni < 4; ni++)
                acc[mi][ni] = __builtin_amdgcn_mfma_f32_16x16x32_bf16(af[mi], bf_[ni], acc[mi][ni], 0, 0, 0);
        __syncthreads();
    }

    #pragma unroll
    for (int ni = 0; ni < 4; ni++) {
        int col = n0 + wc * 64 + ni * 16 + l15;
        float bv = b1[col];
        #pragma unroll
        for (int mi = 0; mi < 4; mi++) {
            int rowb = m0 + wr * 64 + mi * 16 + lquad * 4;
            #pragma unroll
            for (int rg = 0; rg < 4; rg++) {
                float v = acc[mi][ni][rg] + bv;
                v = v >= 0.f ? v : NEG * v;
                H[(rowb + rg) * DIM + col] = f2bf(v);
            }
        }
    }
}

// ---------------- GEMM 1: distances -> packed argmin per row ----------------
__launch_bounds__(256, 2)
__global__ void k_dist(const unsigned short* __restrict__ Amel,
                       const unsigned short* __restrict__ Bemb,
                       const float* __restrict__ enorm,
                       unsigned int* __restrict__ p_pmin) {
    __shared__ __align__(16) unsigned short sA[2][4096], sB[2][4096];
    __shared__ float sEn[1024];
    __shared__ unsigned int red_pm[256];
    int tid = threadIdx.x;
    int w = tid >> 6, lane = tid & 63;
    int wr = w >> 1, wc = w & 1;
    int lquad = lane >> 4, l15 = lane & 15;
    int mt = blockIdx.x >> 3, split = blockIdx.x & 7;
    int m0 = mt * 128, nbase = split * (NEMB / NSPLIT);

    int e0 = w * 512 + lane * 8;
    int r0 = e0 >> 5, ce = e0 & 31;
    int uA = w * 512;   // wave-uniform LDS base (elements)
    const unsigned short* gA = Amel + (m0 + r0) * DIM + ce;
    const unsigned short* gB = Bemb + (nbase + r0) * DIM + ce;

    int offA[4], offB[4];
    #pragma unroll
    for (int i = 0; i < 4; i++) {
        offA[i] = (wr * 64 + i * 16 + l15) * 32 + lquad * 8;
        offB[i] = (wc * 64 + i * 16 + l15) * 32 + lquad * 8;
    }

    // stage enorm (recentred) into LDS so the epilogue never issues global loads
    #pragma unroll
    for (int j = 0; j < 4; j++)
        sEn[tid + j * 256] = enorm[nbase + tid + j * 256] - 512.0f;

    // prologue: tiles 0 and 1 in flight
    ISSUE_TILE(0, 0);
    ISSUE_TILE(1, 1);

    f32x4 acc[4][4];
    #pragma unroll
    for (int mi = 0; mi < 4; mi++)
        #pragma unroll
        for (int ni = 0; ni < 4; ni++) acc[mi][ni] = 0;

    unsigned int pmin[16];
    #pragma unroll
    for (int r = 0; r < 16; r++) pmin[r] = 0xFFFFFFFFu;

    for (int g = 0; g < NG; g += 2) {
        // ---- tile g (buf 0) ----
        pipe_barrier();            // waits tile g's 4 loads; g+1's stay in flight
        COMPUTE_TILE(0);
        plain_barrier();           // everyone done reading buf0
        ISSUE_TILE(g + 2, 0);
        // ---- tile g+1 (buf 1) ----
        pipe_barrier();
        COMPUTE_TILE(1);
        if (((g + 1) & 15) == 15) {
            int c0off = ((g + 1) >> 4) << 7;
            #pragma unroll
            for (int ni = 0; ni < 4; ni++) {
                int j = c0off + wc * 64 + ni * 16 + l15;
                float en = sEn[j];
                unsigned int cl = (unsigned int)(nbase + j);
                #pragma unroll
                for (int mi = 0; mi < 4; mi++)
                    #pragma unroll
                    for (int rg = 0; rg < 4; rg++) {
                        float d = fmaf(-2.f, acc[mi][ni][rg], en);
                        unsigned int pk = (fkey(d) & 0xFFFFE000u) | cl;
                        int r = mi * 4 + rg;
                        pmin[r] = pmin[r] < pk ? pmin[r] : pk;
                        acc[mi][ni][rg] = 0.f;
                    }
            }
        }
        plain_barrier();
        ISSUE_TILE(g + 3, 1);
    }

    #pragma unroll
    for (int r = 0; r < 16; r++)
        #pragma unroll
        for (int d = 1; d < 16; d <<= 1) {
            unsigned int o = (unsigned int)__shfl_xor((int)pmin[r], d);
            pmin[r] = pmin[r] < o ? pmin[r] : o;
        }
    if (l15 == 0) {
        #pragma unroll
        for (int mi = 0; mi < 4; mi++)
            #pragma unroll
            for (int rg = 0; rg < 4; rg++)
                red_pm[(wr * 64 + mi * 16 + lquad * 4 + rg) * 2 + wc] = pmin[mi * 4 + rg];
    }
    __syncthreads();
    if (tid < 128) {
        unsigned int a = red_pm[2 * tid], b = red_pm[2 * tid + 1];
        p_pmin[split * BSZ + m0 + tid] = a < b ? a : b;
    }
}

// ---------------- GEMM 2: logits -> sum(exp) + packed argmax per row ----------------
__launch_bounds__(256, 2)
__global__ void k_logits(const unsigned short* __restrict__ Ah,
                         const unsigned short* __restrict__ Bw2,
                         const float* __restrict__ b2,
                         float* __restrict__ p_s,
                         unsigned int* __restrict__ p_pmax) {
    __shared__ __align__(16) unsigned short sA[2][4096], sB[2][4096];
    __shared__ float sBias[1024];
    __shared__ float red_s[256];
    __shared__ unsigned int red_pm[256];
    int tid = threadIdx.x;
    int w = tid >> 6, lane = tid & 63;
    int wr = w >> 1, wc = w & 1;
    int lquad = lane >> 4, l15 = lane & 15;
    int mt = blockIdx.x >> 3, split = blockIdx.x & 7;
    int m0 = mt * 128, nbase = split * (NEMB / NSPLIT);

    int e0 = w * 512 + lane * 8;
    int r0 = e0 >> 5, ce = e0 & 31;
    int uA = w * 512;
    const unsigned short* gA = Ah + (m0 + r0) * DIM + ce;
    const unsigned short* gB = Bw2 + (nbase + r0) * DIM + ce;

    int offA[4], offB[4];
    #pragma unroll
    for (int i = 0; i < 4; i++) {
        offA[i] = (wr * 64 + i * 16 + l15) * 32 + lquad * 8;
        offB[i] = (wc * 64 + i * 16 + l15) * 32 + lquad * 8;
    }

    #pragma unroll
    for (int j = 0; j < 4; j++)
        sBias[tid + j * 256] = b2[nbase + tid + j * 256];

    ISSUE_TILE(0, 0);
    ISSUE_TILE(1, 1);

    f32x4 acc[4][4];
    #pragma unroll
    for (int mi = 0; mi < 4; mi++)
        #pragma unroll
        for (int ni = 0; ni < 4; ni++) acc[mi][ni] = 0;

    float s[16];
    unsigned int pmax[16];
    #pragma unroll
    for (int r = 0; r < 16; r++) { s[r] = 0.f; pmax[r] = 0u; }

    for (int g = 0; g < NG; g += 2) {
        // ---- tile g (buf 0) ----
        pipe_barrier();
        COMPUTE_TILE(0);
        plain_barrier();
        ISSUE_TILE(g + 2, 0);
        // ---- tile g+1 (buf 1) ----
        pipe_barrier();
        COMPUTE_TILE(1);
        if (((g + 1) & 15) == 15) {
            int c0off = ((g + 1) >> 4) << 7;
            #pragma unroll
            for (int ni = 0; ni < 4; ni++) {
                int j = c0off + wc * 64 + ni * 16 + l15;
                float bb = sBias[j];
                unsigned int ic = (unsigned int)(NEMB - 1 - (nbase + j));
                #pragma unroll
                for (int mi = 0; mi < 4; mi++)
                    #pragma unroll
                    for (int rg = 0; rg < 4; rg++) {
                        float logit = acc[mi][ni][rg] + bb;
                        int r = mi * 4 + rg;
                        s[r] += __expf(logit);     // logits are O(1): no max-shift needed
                        unsigned int pk = (fkey(logit) & 0xFFFFE000u) | ic;
                        pmax[r] = pmax[r] > pk ? pmax[r] : pk;
                        acc[mi][ni][rg] = 0.f;
                    }
            }
        }
        plain_barrier();
        ISSUE_TILE(g + 3, 1);
    }

    #pragma unroll
    for (int r = 0; r < 16; r++)
        #pragma unroll
        for (int d = 1; d < 16; d <<= 1) {
            s[r] += __shfl_xor(s[r], d);
            unsigned int o = (unsigned int)__shfl_xor((int)pmax[r], d);
            pmax[r] = pmax[r] > o ? pmax[r] : o;
        }
    if (l15 == 0) {
        #pragma unroll
        for (int mi = 0; mi < 4; mi++)
            #pragma unroll
            for (int rg = 0; rg < 4; rg++) {
                int r2 = (wr * 64 + mi * 16 + lquad * 4 + rg) * 2 + wc;
                red_s[r2] = s[mi * 4 + rg];
                red_pm[r2] = pmax[mi * 4 + rg];
            }
    }
    __syncthreads();
    if (tid < 128) {
        float S = red_s[2 * tid] + red_s[2 * tid + 1];
        unsigned int a = red_pm[2 * tid], b = red_pm[2 * tid + 1];
        int pidx = split * BSZ + m0 + tid;
        p_s[pidx] = S;
        p_pmax[pidx] = a > b ? a : b;
    }
}

// ---------------- merge split partials per row ----------------
__global__ void k_merge(const float* __restrict__ p_s, const unsigned int* __restrict__ p_pmax,
                        const unsigned int* __restrict__ p_pmin,
                        int* __restrict__ mel_idx, float* __restrict__ lse,
                        float* __restrict__ match) {
    int r = blockIdx.x * blockDim.x + threadIdx.x;
    if (r >= BSZ) return;
    float S = 0.f; unsigned int PM = 0u, PN = 0xFFFFFFFFu;
    #pragma unroll
    for (int sp = 0; sp < NSPLIT; sp++) {
        S += p_s[sp * BSZ + r];
        unsigned int a = p_pmax[sp * BSZ + r];
        PM = PM > a ? PM : a;
        unsigned int b = p_pmin[sp * BSZ + r];
        PN = PN < b ? PN : b;
    }
    int eidx = (NEMB - 1) - (int)(PM & 0x1FFFu);
    int midx = (int)(PN & 0x1FFFu);
    mel_idx[r] = midx;
    lse[r] = __logf(S);
    match[r] = (eidx == midx) ? 1.f : 0.f;
}

// ---------------- gather picked logit, per-row loss ----------------
__device__ __forceinline__ float dot2bf(unsigned int h, unsigned int w) {
    return bf2f((unsigned short)(h & 0xffff)) * bf2f((unsigned short)(w & 0xffff))
         + bf2f((unsigned short)(h >> 16))    * bf2f((unsigned short)(w >> 16));
}

__global__ void k_gather(const unsigned short* __restrict__ H,
                         const unsigned short* __restrict__ W2b,
                         const float* __restrict__ b2,
                         const int* __restrict__ mel_idx,
                         const float* __restrict__ lse,
                         float* __restrict__ loss) {
    int r = blockIdx.x * 4 + (threadIdx.x >> 6);
    int lane = threadIdx.x & 63;
    int idx = mel_idx[r];
    uint4 hv = *(const uint4*)(H + r * DIM + lane * 8);
    uint4 wv = *(const uint4*)(W2b + idx * DIM + lane * 8);
    float s = dot2bf(hv.x, wv.x) + dot2bf(hv.y, wv.y) + dot2bf(hv.z, wv.z) + dot2bf(hv.w, wv.w);
    #pragma unroll
    for (int d = 1; d < 64; d <<= 1) s += __shfl_xor(s, d);
    if (lane == 0) loss[r] = lse[r] - (s + b2[idx]);
}

// ---------------- final scalar reduction ----------------
__global__ void k_reduce(const float* __restrict__ loss, const float* __restrict__ match,
                         float* __restrict__ out) {
    __shared__ float sl[256], sm[256];
    int tid = threadIdx.x;
    float a = 0.f, b = 0.f;
    for (int i = tid; i < BSZ; i += 256) { a += loss[i]; b += match[i]; }
    sl[tid] = a; sm[tid] = b;
    __syncthreads();
    for (int s = 128; s > 0; s >>= 1) {
        if (tid < s) { sl[tid] += sl[tid + s]; sm[tid] += sm[tid + s]; }
        __syncthreads();
    }
    if (tid == 0) { out[0] = sl[0] / (float)BSZ; out[1] = sm[0] / (float)BSZ; }
}

extern "C" void kernel_launch(void* const* d_in, const int* in_sizes, int n_in,
                              void* d_out, int out_size, void* d_ws, size_t ws_size,
                              hipStream_t stream) {
    const float* eeg = (const float*)d_in[0];
    const float* mel = (const float*)d_in[1];
    const float* emb = (const float*)d_in[2];
    const float* W1  = (const float*)d_in[3];
    const float* b1  = (const float*)d_in[4];
    const float* W2  = (const float*)d_in[5];
    const float* b2  = (const float*)d_in[6];
    float* out = (float*)d_out;

    unsigned short* ws_mel = (unsigned short*)d_ws;
    unsigned short* ws_eeg = ws_mel + (size_t)BSZ * DIM;
    unsigned short* ws_h   = ws_eeg + (size_t)BSZ * DIM;
    unsigned short* ws_emb = ws_h   + (size_t)BSZ * DIM;
    unsigned short* ws_w2  = ws_emb + (size_t)NEMB * DIM;
    unsigned short* ws_w1  = ws_w2  + (size_t)NEMB * DIM;
    float* ws_en  = (float*)(ws_w1 + (size_t)DIM * DIM);
    float* p_s    = ws_en + NEMB;
    unsigned int* p_pmax = (unsigned int*)(p_s + (size_t)NSPLIT * BSZ);
    unsigned int* p_pmin = p_pmax + (size_t)NSPLIT * BSZ;
    int*   mel_i  = (int*)(p_pmin + (size_t)NSPLIT * BSZ);
    float* lse    = (float*)(mel_i + BSZ);
    float* match  = lse + BSZ;
    float* loss   = match + BSZ;

    k_convert_all<<<1024, 256, 0, stream>>>(eeg, mel, emb, W2, W1,
                                            ws_eeg, ws_mel, ws_emb, ws_w2, ws_w1);
    k_enorm<<<NEMB / 4, 256, 0, stream>>>(emb, ws_en);
    k_hgemm<<<(BSZ / 128) * (DIM / 128), 256, 0, stream>>>(ws_eeg, ws_w1, b1, ws_h);
    k_dist<<<(BSZ / 128) * NSPLIT, 256, 0, stream>>>(ws_mel, ws_emb, ws_en, p_pmin);
    k_logits<<<(BSZ / 128) * NSPLIT, 256, 0, stream>>>(ws_h, ws_w2, b2, p_s, p_pmax);
    k_merge<<<BSZ / 256, 256, 0, stream>>>(p_s, p_pmax, p_pmin, mel_i, lse, match);
    k_gather<<<BSZ / 4, 256, 0, stream>>>(ws_h, ws_w2, b2, mel_i, lse, loss);
    k_reduce<<<1, 256, 0, stream>>>(loss, match, out);
}